// Round 6
// baseline (491.195 us; speedup 1.0000x reference)
//
#include <hip/hip_runtime.h>
#include <hip/hip_bf16.h>
#include <stdint.h>

// QuantizedLinear: out_f32[512,16384] = x_f32[512,4096] @ (qw_i32 * scales)^T + bias
// dtypes (verified round 3): x fp32, qw int32, scales fp32, bias fp32, out fp32.
//
// Round-13: STRUCTURAL RESET to the measured m97 template.
// r11 (1-barrier) vs r12 (4-phase+counted-vmcnt+setprio) produced byte-identical
// counters (163-172us, Mfma 16%, VALU 13%, HBM 25%, conflicts 6291456 exactly) --
// third schedule-restructure null in a row. Conclusion: the critical resource is
// something ALL variants share: the in-loop VALU-dequant -> reg ds_write producer
// machinery and its lgkm coupling. Remove it entirely:
//  - NEW pack_w prepass: dequant qw(int32)+scales ONCE into wb = fragment-ordered
//    bf16 [slab 0..255][kb 0..31][chunk 0..1023][8 bf16] (128 MB in workspace).
//    Coalesced 16B writes; strided reads consume full 128B lines. Pure streaming,
//    ~61us floor (read 256 + write 128 MB at 6.3 TB/s).
//  - qlin_gemm main loop = m97 structure (874 TF measured on gfx950): B staged
//    LDS via __builtin_amdgcn_global_load_lds width-16 (2 insts/thread, LINEAR
//    dest = fragment order, no swizzle anywhere), double-buffered, ONE plain
//    __syncthreads per iter; A register-direct from xp (unchanged prepass);
//    32 MFMA per wave-iter. No dequant, no ds_write, no producer mapping in loop.
//  - grid 512: slab = bid&255, h = bid>>8 -> the two M-half blocks of a slab sit
//    256 apart = SAME XCD (256%8==0) -> wb tile shared in that XCD's L2.
// Keeps (verified in r11/r12, absmax 0.125): pack_x fragment layout, A-frag
// mapping, MFMA call shape, epilogue/store mapping.

#define MM 512
#define NN 16384
#define KK 4096
#define BN 64
#define BK 128
#define NKB (KK / BK)    // 32
#define NSLAB (NN / BN)  // 256

typedef __bf16 bf16x8 __attribute__((ext_vector_type(8)));
typedef float floatx4 __attribute__((ext_vector_type(4)));

__device__ __forceinline__ unsigned int pk_bf16_rtn(float lo, float hi) {
    __hip_bfloat162 h = __float22bfloat162_rn(float2{lo, hi});
    return *reinterpret_cast<unsigned int*>(&h);
}

__device__ __forceinline__ uint4 deq8(const int4 q0, const int4 q1, const float s) {
    uint4 u;
    u.x = pk_bf16_rtn((float)q0.x * s, (float)q0.y * s);
    u.y = pk_bf16_rtn((float)q0.z * s, (float)q0.w * s);
    u.z = pk_bf16_rtn((float)q1.x * s, (float)q1.y * s);
    u.w = pk_bf16_rtn((float)q1.z * s, (float)q1.w * s);
    return u;
}

// async global->LDS, 16B per lane; LDS dest = wave-uniform base + lane*16 (m104).
__device__ __forceinline__ void gload16(const void* g, void* l) {
    __builtin_amdgcn_global_load_lds(
        (const __attribute__((address_space(1))) void*)g,
        (__attribute__((address_space(3))) void*)l, 16, 0, 0);
}

// ---- prepass 1: x fp32 -> bf16, packed in MFMA A-fragment order ----
// xp element index: (((kb*4 + ks)*32 + mt)*64 + lane)*8,
//   holding x[mt*16 + (lane&15)][kb*128 + ks*32 + (lane>>4)*8 .. +8]
__global__ __launch_bounds__(256) void pack_x(const float* __restrict__ x,
                                              unsigned short* __restrict__ xp) {
    const int t    = blockIdx.x * 256 + threadIdx.x;   // 0..262143
    const int lane = t & 63;
    const int mt   = (t >> 6) & 31;
    const int ks   = (t >> 11) & 3;
    const int kb   = t >> 13;
    const int m    = mt * 16 + (lane & 15);
    const int k    = kb * 128 + ks * 32 + (lane >> 4) * 8;
    const float* px = x + (size_t)m * KK + k;
    const float4 a = *(const float4*)px;
    const float4 b = *(const float4*)(px + 4);
    uint4 o;
    o.x = pk_bf16_rtn(a.x, a.y);
    o.y = pk_bf16_rtn(a.z, a.w);
    o.z = pk_bf16_rtn(b.x, b.y);
    o.w = pk_bf16_rtn(b.z, b.w);
    *(uint4*)(xp + (size_t)t * 8) = o;   // fully coalesced 16B/thread
}

// ---- prepass 2: dequant qw -> wb bf16, fragment-ordered per (slab, kb) ----
// wb tile (slab,kb): 1024 chunks of 16B. chunk c: f=c>>6 (=ks*4+j), l=c&63;
//   holds W[col = slab*64 + j*16 + (l&15)][k = kb*128 + ks*32 + (l>>4)*8 .. +8].
// Writes perfectly coalesced (thread u -> chunk u, u+512); reads are 16-row
// strided but consume full 128B lines (each line read exactly once).
__global__ __launch_bounds__(512) void pack_w(const int* __restrict__ qw,
                                              const float* __restrict__ scales,
                                              unsigned short* __restrict__ wb) {
    const int slab = blockIdx.x >> 5;   // 0..255
    const int kb   = blockIdx.x & 31;   // 0..31
    const int u    = threadIdx.x;       // 0..511
    unsigned short* wt = wb + (size_t)(slab * 32 + kb) * 8192;   // 1024*8 shorts
#pragma unroll
    for (int half = 0; half < 2; ++half) {
        const int c  = u + half * 512;
        const int f  = c >> 6;
        const int l  = c & 63;
        const int ks = f >> 2;
        const int j  = f & 3;
        const int col = slab * 64 + j * 16 + (l & 15);
        const int k   = kb * 128 + ks * 32 + (l >> 4) * 8;
        const int* qp = qw + (size_t)col * KK + k;
        const int4 q0 = *(const int4*)qp;
        const int4 q1 = *(const int4*)(qp + 4);
        const float s = scales[(size_t)col * 64 + (k >> 6)];
        const uint4 uu = deq8(q0, q1, s);
        *(uint4*)(wt + (size_t)c * 8) = uu;
    }
}

// ---- main GEMM: m97 template. B via global_load_lds dbuf, A register-direct ----
__global__ __launch_bounds__(512, 4) void qlin_gemm(
    const unsigned short* __restrict__ xp,      // packed bf16 x (4 MB)
    const unsigned short* __restrict__ wb,      // packed bf16 W (128 MB)
    const float* __restrict__ bias,             // fp32 [16384]
    float* __restrict__ out)                    // fp32 [512,16384]
{
    __shared__ unsigned short sB[2][BN * BK];   // fragment-ordered, 2 x 16 KB

    const int t    = threadIdx.x;     // 0..511
    const int lane = t & 63;
    const int wv   = t >> 6;          // wave 0..7 -> M strip [h*256 + wv*32, +32)
    const int ln   = lane & 15;
    const int quad = lane >> 4;
    const int slab = blockIdx.x & 255;          // column slab
    const int h    = blockIdx.x >> 8;           // M half; slab-pair 256 apart = same XCD
    const int n0   = slab * BN;

    const unsigned short* wbase = wb + (size_t)slab * 32 * 8192;  // this slab's 32 tiles

    floatx4 acc[2][4];
#pragma unroll
    for (int i = 0; i < 2; ++i)
#pragma unroll
        for (int j = 0; j < 4; ++j)
            acc[i][j] = (floatx4)0.0f;

    // ---- prologue: stage tile 0 into buf0 ----
    {
        const unsigned short* src = wbase + (size_t)t * 8;
        gload16(src,            &sB[0][wv * 512]);          // chunks 0..511
        gload16(src + 512 * 8,  &sB[0][4096 + wv * 512]);   // chunks 512..1023
    }
    __syncthreads();   // tile 0 resident

    for (int kb = 0; kb < NKB; ++kb) {
        const unsigned short* sb = sB[kb & 1];

        // ---- issue next tile's stage into the other buffer (in flight across
        // this iteration's compute; drained by the end-of-iter barrier) ----
        if (kb + 1 < NKB) {
            const unsigned short* src = wbase + (size_t)(kb + 1) * 8192 + (size_t)t * 8;
            unsigned short* d0 = &sB[(kb + 1) & 1][wv * 512];
            unsigned short* d1 = &sB[(kb + 1) & 1][4096 + wv * 512];
            gload16(src,           d0);
            gload16(src + 512 * 8, d1);
        }

        // ---- A fragments for kb (register-direct from xp; L2/L3-resident) ----
        bf16x8 a[4][2];
#pragma unroll
        for (int ks = 0; ks < 4; ++ks) {
            const unsigned short* ap =
                xp + (size_t)kb * 65536
                   + (size_t)((ks * 32 + h * 16 + wv * 2) * 64 + lane) * 8;
            a[ks][0] = *(const bf16x8*)(ap);
            a[ks][1] = *(const bf16x8*)(ap + 512);
        }

        // ---- compute: 16 ds_read_b128 + 32 MFMA ----
#pragma unroll
        for (int ks = 0; ks < 4; ++ks) {
#pragma unroll
            for (int jj = 0; jj < 4; jj += 2) {
                bf16x8 b0 = *(const bf16x8*)(sb + ((ks * 4 + jj) * 64 + lane) * 8);
                bf16x8 b1 = *(const bf16x8*)(sb + ((ks * 4 + jj + 1) * 64 + lane) * 8);
                acc[0][jj]     = __builtin_amdgcn_mfma_f32_16x16x32_bf16(a[ks][0], b0, acc[0][jj], 0, 0, 0);
                acc[1][jj]     = __builtin_amdgcn_mfma_f32_16x16x32_bf16(a[ks][1], b0, acc[1][jj], 0, 0, 0);
                acc[0][jj + 1] = __builtin_amdgcn_mfma_f32_16x16x32_bf16(a[ks][0], b1, acc[0][jj + 1], 0, 0, 0);
                acc[1][jj + 1] = __builtin_amdgcn_mfma_f32_16x16x32_bf16(a[ks][1], b1, acc[1][jj + 1], 0, 0, 0);
            }
        }

        // ---- end-of-iter barrier (m97 semantics: full drain, incl. the stage;
        // cross-block overlap on the CU hides the drain) ----
        if (kb + 1 < NKB) __syncthreads();
    }

    // ---- epilogue: + bias, store fp32 ----
#pragma unroll
    for (int j = 0; j < 4; ++j) {
        const int n = n0 + j * 16 + ln;
        const float bv = bias[n];
#pragma unroll
        for (int i = 0; i < 2; ++i) {
            const int mbase = h * 256 + wv * 32 + i * 16 + quad * 4;
#pragma unroll
            for (int rr = 0; rr < 4; ++rr)
                out[(size_t)(mbase + rr) * NN + n] = acc[i][j][rr] + bv;
        }
    }
}

// ---- fallback (workspace too small; never expected to trigger) ----
__global__ __launch_bounds__(256) void qlin_naive(
    const float* __restrict__ x, const int* __restrict__ qw,
    const float* __restrict__ scales, const float* __restrict__ bias,
    float* __restrict__ out) {
    const int n = blockIdx.x * 256 + threadIdx.x;   // 0..16383
    const int m = blockIdx.y;                       // 0..511
    if (n >= NN || m >= MM) return;
    float accv = 0.0f;
    for (int kb = 0; kb < 64; ++kb) {
        const float s = scales[(size_t)n * 64 + kb];
        float part = 0.0f;
        for (int k = kb * 64; k < kb * 64 + 64; ++k)
            part += x[(size_t)m * KK + k] * (float)qw[(size_t)n * KK + k];
        accv += part * s;
    }
    out[(size_t)m * NN + n] = accv + bias[n];
}

extern "C" void kernel_launch(void* const* d_in, const int* in_sizes, int n_in,
                              void* d_out, int out_size, void* d_ws, size_t ws_size,
                              hipStream_t stream) {
    const float* x    = (const float*)d_in[0];
    const int* qw     = (const int*)d_in[1];
    const float* scl  = (const float*)d_in[2];
    const float* bias = (const float*)d_in[3];
    float* out        = (float*)d_out;

    const size_t XPB = (size_t)MM * KK * sizeof(unsigned short);   // 4 MB
    const size_t WBB = (size_t)NN * KK * sizeof(unsigned short);   // 128 MB

    if (ws_size >= XPB + WBB) {
        unsigned short* xp = (unsigned short*)d_ws;
        unsigned short* wb = (unsigned short*)((char*)d_ws + XPB);
        pack_x<<<dim3(MM * KK / (256 * 8)), dim3(256), 0, stream>>>(x, xp);
        pack_w<<<dim3(NSLAB * 32), dim3(512), 0, stream>>>(qw, scl, wb);
        qlin_gemm<<<dim3(NSLAB * 2), dim3(512), 0, stream>>>(xp, wb, bias, out);
    } else {
        qlin_naive<<<dim3(NN / 256, MM), dim3(256), 0, stream>>>(x, qw, scl, bias, out);
    }
}

// Round 7
// 490.082 us; speedup vs baseline: 1.0023x; 1.0023x over previous
//
#include <hip/hip_runtime.h>
#include <hip/hip_bf16.h>
#include <stdint.h>

// QuantizedLinear: out_f32[512,16384] = x_f32[512,4096] @ (qw_i32 * scales)^T + bias
// dtypes (verified round 3): x fp32, qw int32, scales fp32, bias fp32, out fp32.
//
// Round-14: coalesce pack_w (LDS-transpose), single-variable vs round-13.
// r13 post-mortem: dur 437 -> 491 (regression). Fixed harness ~270us, pack_x
// ~4us => pack_w + gemm ~= 217us, neither in top-5 (each < 160us). Suspect:
// pack_w's qw reads were line-complete but not instruction-coalesced (each
// dwordx4 touched 64 distinct 128B lines at 16B/line -> 8x line-request rate).
// Fix: one 256-thr block per (slab,kb) tile; phase 1 reads CONTIGUOUS 128B
// per thread (perfect stream), dequants, stores LDS [64][136] bf16 (pad 136:
// fragment reads <=2-way bank aliasing = free); phase 2 writes fragment-order
// chunks with fully coalesced 16B/lane stores. wb bit-identical to r13.
// gemm / pack_x / launcher byte-identical to r13 (m97 template: global_load_lds
// double-buffer, plain __syncthreads, A register-direct from xp).
// Expected: pack_w ~65-75us. World A (pack_w was ~140): dur -> ~415-430.
// World B (pack_w was already ~80): dur ~485 -> gemm pinned at ~135us, next
// round restructures the gemm.

#define MM 512
#define NN 16384
#define KK 4096
#define BN 64
#define BK 128
#define NKB (KK / BK)    // 32
#define NSLAB (NN / BN)  // 256

typedef __bf16 bf16x8 __attribute__((ext_vector_type(8)));
typedef float floatx4 __attribute__((ext_vector_type(4)));

__device__ __forceinline__ unsigned int pk_bf16_rtn(float lo, float hi) {
    __hip_bfloat162 h = __float22bfloat162_rn(float2{lo, hi});
    return *reinterpret_cast<unsigned int*>(&h);
}

__device__ __forceinline__ uint4 deq8(const int4 q0, const int4 q1, const float s) {
    uint4 u;
    u.x = pk_bf16_rtn((float)q0.x * s, (float)q0.y * s);
    u.y = pk_bf16_rtn((float)q0.z * s, (float)q0.w * s);
    u.z = pk_bf16_rtn((float)q1.x * s, (float)q1.y * s);
    u.w = pk_bf16_rtn((float)q1.z * s, (float)q1.w * s);
    return u;
}

// async global->LDS, 16B per lane; LDS dest = wave-uniform base + lane*16 (m104).
__device__ __forceinline__ void gload16(const void* g, void* l) {
    __builtin_amdgcn_global_load_lds(
        (const __attribute__((address_space(1))) void*)g,
        (__attribute__((address_space(3))) void*)l, 16, 0, 0);
}

// ---- prepass 1: x fp32 -> bf16, packed in MFMA A-fragment order ----
// xp element index: (((kb*4 + ks)*32 + mt)*64 + lane)*8,
//   holding x[mt*16 + (lane&15)][kb*128 + ks*32 + (lane>>4)*8 .. +8]
__global__ __launch_bounds__(256) void pack_x(const float* __restrict__ x,
                                              unsigned short* __restrict__ xp) {
    const int t    = blockIdx.x * 256 + threadIdx.x;   // 0..262143
    const int lane = t & 63;
    const int mt   = (t >> 6) & 31;
    const int ks   = (t >> 11) & 3;
    const int kb   = t >> 13;
    const int m    = mt * 16 + (lane & 15);
    const int k    = kb * 128 + ks * 32 + (lane >> 4) * 8;
    const float* px = x + (size_t)m * KK + k;
    const float4 a = *(const float4*)px;
    const float4 b = *(const float4*)(px + 4);
    uint4 o;
    o.x = pk_bf16_rtn(a.x, a.y);
    o.y = pk_bf16_rtn(a.z, a.w);
    o.z = pk_bf16_rtn(b.x, b.y);
    o.w = pk_bf16_rtn(b.z, b.w);
    *(uint4*)(xp + (size_t)t * 8) = o;   // fully coalesced 16B/thread
}

// ---- prepass 2 (v2): dequant qw -> wb, LDS-transposed, both sides coalesced ----
// One block per (slab,kb) tile. Tile = 64 cols x 128 k.
// Phase 1: thread u reads a CONTIGUOUS 128B of qw: row r=u>>2, ints [q*32, q*32+32)
//   of the tile (q=u&3). One scale per thread (q*32 spans exactly one 64-block).
//   Dequant -> LDS lw[64][136] bf16 (pad 136: phase-2 col-stride 272B = 68 dwords
//   -> bank advance 4/col -> worst 2-way aliasing, free per m136).
// Phase 2: thread u emits chunks c = u + {0,256,512,768}: f=c>>6 (=ks*4+j), l=c&63;
//   reads lw[j*16+(l&15)][ks*32+(l>>4)*8 ..+8] (16B), writes wt+c*8 -- lanes
//   consecutive => fully coalesced 1KB/wave stores. Chunk contents identical to r13.
__global__ __launch_bounds__(256) void pack_w(const int* __restrict__ qw,
                                              const float* __restrict__ scales,
                                              unsigned short* __restrict__ wb) {
    __shared__ unsigned short lw[64][136];
    const int tile = blockIdx.x;        // 0..8191
    const int slab = tile >> 5;
    const int kb   = tile & 31;
    const int u    = threadIdx.x;       // 0..255

    // ---- phase 1: coalesced read + dequant + LDS store ----
    const int r   = u >> 2;             // col within slab, 0..63
    const int q   = u & 3;              // k-quarter (32 ints)
    const int col = slab * 64 + r;
    const int k0  = kb * 128 + q * 32;
    const int* qp = qw + (size_t)col * KK + k0;
    const float s = scales[(size_t)col * 64 + (k0 >> 6)];
#pragma unroll
    for (int i = 0; i < 4; ++i) {
        const int4 q0 = *(const int4*)(qp + i * 8);
        const int4 q1 = *(const int4*)(qp + i * 8 + 4);
        const uint4 uu = deq8(q0, q1, s);
        *(uint4*)&lw[r][q * 32 + i * 8] = uu;
    }
    __syncthreads();

    // ---- phase 2: fragment-order gather from LDS, coalesced global store ----
    unsigned short* wt = wb + (size_t)tile * 8192;   // 1024 chunks * 8 shorts
#pragma unroll
    for (int hc = 0; hc < 4; ++hc) {
        const int c  = u + hc * 256;
        const int f  = c >> 6;
        const int l  = c & 63;
        const int ks = f >> 2;
        const int j  = f & 3;
        const uint4 v = *(const uint4*)&lw[j * 16 + (l & 15)][ks * 32 + (l >> 4) * 8];
        *(uint4*)(wt + (size_t)c * 8) = v;
    }
}

// ---- main GEMM: m97 template. B via global_load_lds dbuf, A register-direct ----
__global__ __launch_bounds__(512, 4) void qlin_gemm(
    const unsigned short* __restrict__ xp,      // packed bf16 x (4 MB)
    const unsigned short* __restrict__ wb,      // packed bf16 W (128 MB)
    const float* __restrict__ bias,             // fp32 [16384]
    float* __restrict__ out)                    // fp32 [512,16384]
{
    __shared__ unsigned short sB[2][BN * BK];   // fragment-ordered, 2 x 16 KB

    const int t    = threadIdx.x;     // 0..511
    const int lane = t & 63;
    const int wv   = t >> 6;          // wave 0..7 -> M strip [h*256 + wv*32, +32)
    const int ln   = lane & 15;
    const int quad = lane >> 4;
    const int slab = blockIdx.x & 255;          // column slab
    const int h    = blockIdx.x >> 8;           // M half; slab-pair 256 apart = same XCD
    const int n0   = slab * BN;

    const unsigned short* wbase = wb + (size_t)slab * 32 * 8192;  // this slab's 32 tiles

    floatx4 acc[2][4];
#pragma unroll
    for (int i = 0; i < 2; ++i)
#pragma unroll
        for (int j = 0; j < 4; ++j)
            acc[i][j] = (floatx4)0.0f;

    // ---- prologue: stage tile 0 into buf0 ----
    {
        const unsigned short* src = wbase + (size_t)t * 8;
        gload16(src,            &sB[0][wv * 512]);          // chunks 0..511
        gload16(src + 512 * 8,  &sB[0][4096 + wv * 512]);   // chunks 512..1023
    }
    __syncthreads();   // tile 0 resident

    for (int kb = 0; kb < NKB; ++kb) {
        const unsigned short* sb = sB[kb & 1];

        // ---- issue next tile's stage into the other buffer (in flight across
        // this iteration's compute; drained by the end-of-iter barrier) ----
        if (kb + 1 < NKB) {
            const unsigned short* src = wbase + (size_t)(kb + 1) * 8192 + (size_t)t * 8;
            unsigned short* d0 = &sB[(kb + 1) & 1][wv * 512];
            unsigned short* d1 = &sB[(kb + 1) & 1][4096 + wv * 512];
            gload16(src,           d0);
            gload16(src + 512 * 8, d1);
        }

        // ---- A fragments for kb (register-direct from xp; L2/L3-resident) ----
        bf16x8 a[4][2];
#pragma unroll
        for (int ks = 0; ks < 4; ++ks) {
            const unsigned short* ap =
                xp + (size_t)kb * 65536
                   + (size_t)((ks * 32 + h * 16 + wv * 2) * 64 + lane) * 8;
            a[ks][0] = *(const bf16x8*)(ap);
            a[ks][1] = *(const bf16x8*)(ap + 512);
        }

        // ---- compute: 16 ds_read_b128 + 32 MFMA ----
#pragma unroll
        for (int ks = 0; ks < 4; ++ks) {
#pragma unroll
            for (int jj = 0; jj < 4; jj += 2) {
                bf16x8 b0 = *(const bf16x8*)(sb + ((ks * 4 + jj) * 64 + lane) * 8);
                bf16x8 b1 = *(const bf16x8*)(sb + ((ks * 4 + jj + 1) * 64 + lane) * 8);
                acc[0][jj]     = __builtin_amdgcn_mfma_f32_16x16x32_bf16(a[ks][0], b0, acc[0][jj], 0, 0, 0);
                acc[1][jj]     = __builtin_amdgcn_mfma_f32_16x16x32_bf16(a[ks][1], b0, acc[1][jj], 0, 0, 0);
                acc[0][jj + 1] = __builtin_amdgcn_mfma_f32_16x16x32_bf16(a[ks][0], b1, acc[0][jj + 1], 0, 0, 0);
                acc[1][jj + 1] = __builtin_amdgcn_mfma_f32_16x16x32_bf16(a[ks][1], b1, acc[1][jj + 1], 0, 0, 0);
            }
        }

        // ---- end-of-iter barrier (m97 semantics: full drain, incl. the stage;
        // cross-block overlap on the CU hides the drain) ----
        if (kb + 1 < NKB) __syncthreads();
    }

    // ---- epilogue: + bias, store fp32 ----
#pragma unroll
    for (int j = 0; j < 4; ++j) {
        const int n = n0 + j * 16 + ln;
        const float bv = bias[n];
#pragma unroll
        for (int i = 0; i < 2; ++i) {
            const int mbase = h * 256 + wv * 32 + i * 16 + quad * 4;
#pragma unroll
            for (int rr = 0; rr < 4; ++rr)
                out[(size_t)(mbase + rr) * NN + n] = acc[i][j][rr] + bv;
        }
    }
}

// ---- fallback (workspace too small; never expected to trigger) ----
__global__ __launch_bounds__(256) void qlin_naive(
    const float* __restrict__ x, const int* __restrict__ qw,
    const float* __restrict__ scales, const float* __restrict__ bias,
    float* __restrict__ out) {
    const int n = blockIdx.x * 256 + threadIdx.x;   // 0..16383
    const int m = blockIdx.y;                       // 0..511
    if (n >= NN || m >= MM) return;
    float accv = 0.0f;
    for (int kb = 0; kb < 64; ++kb) {
        const float s = scales[(size_t)n * 64 + kb];
        float part = 0.0f;
        for (int k = kb * 64; k < kb * 64 + 64; ++k)
            part += x[(size_t)m * KK + k] * (float)qw[(size_t)n * KK + k];
        accv += part * s;
    }
    out[(size_t)m * NN + n] = accv + bias[n];
}

extern "C" void kernel_launch(void* const* d_in, const int* in_sizes, int n_in,
                              void* d_out, int out_size, void* d_ws, size_t ws_size,
                              hipStream_t stream) {
    const float* x    = (const float*)d_in[0];
    const int* qw     = (const int*)d_in[1];
    const float* scl  = (const float*)d_in[2];
    const float* bias = (const float*)d_in[3];
    float* out        = (float*)d_out;

    const size_t XPB = (size_t)MM * KK * sizeof(unsigned short);   // 4 MB
    const size_t WBB = (size_t)NN * KK * sizeof(unsigned short);   // 128 MB

    if (ws_size >= XPB + WBB) {
        unsigned short* xp = (unsigned short*)d_ws;
        unsigned short* wb = (unsigned short*)((char*)d_ws + XPB);
        pack_x<<<dim3(MM * KK / (256 * 8)), dim3(256), 0, stream>>>(x, xp);
        pack_w<<<dim3(NSLAB * 32), dim3(256), 0, stream>>>(qw, scl, wb);
        qlin_gemm<<<dim3(NSLAB * 2), dim3(512), 0, stream>>>(xp, wb, bias, out);
    } else {
        qlin_naive<<<dim3(NN / 256, MM), dim3(256), 0, stream>>>(x, qw, scl, bias, out);
    }
}